// Round 3
// baseline (302.833 us; speedup 1.0000x reference)
//
#include <hip/hip_runtime.h>
#include <hip/hip_bf16.h>

#define NN 100000
#define EE 400000
#define EBLK ((EE + 255) / 256)   // 1563 edge blocks in prep

typedef unsigned short u16;
typedef unsigned int u32;
typedef __attribute__((ext_vector_type(4))) float floatx4;
typedef __attribute__((ext_vector_type(8))) short shortx8;
typedef __attribute__((ext_vector_type(4))) unsigned short ushortx4;

__device__ __forceinline__ u16 f2bf(float f) {
    unsigned u = __float_as_uint(f);
    u += 0x7FFFu + ((u >> 16) & 1u);
    return (u16)(u >> 16);
}

// ---- prep: edge blocks set degree BITMASKS via device-scope atomicOr
//      (no byte-scatter line ping-pong across XCD L2s);
//      tail blocks convert W -> bf16 in MFMA A-FRAGMENT order:
//      Wtf[mat][chunk=ks*8+nt][lane][j] = W[mat][k][n],
//      k = ks*32 + (lane>>4)*8 + j, n = nt*16 + (lane&15).
__global__ __launch_bounds__(256) void prep(
    const int* __restrict__ daa, const int* __restrict__ dab, const int* __restrict__ dba,
    u32* __restrict__ bm,                 // [3][3200] bitmask words
    const float* __restrict__ Wr0, const float* __restrict__ Wr1,
    u16* __restrict__ Wtf) {              // [4][16384]
    int b = blockIdx.x, t = threadIdx.x;
    if (b < EBLK) {
        int e = b * 256 + t;
        if (e < EE) {
            int d0 = daa[e], d1 = dab[e], d2 = dba[e];
            atomicOr(&bm[d0 >> 5], 1u << (d0 & 31));
            atomicOr(&bm[3200 + (d1 >> 5)], 1u << (d1 & 31));
            atomicOr(&bm[6400 + (d2 >> 5)], 1u << (d2 & 31));
        }
    } else {
        int idx = (b - EBLK) * 256 + t;    // [0, 4*16384)
        int mat = idx >> 14;
        int fidx = idx & 16383;
        int chunk = fidx >> 9;             // ks*8 + nt
        int lane = (fidx >> 3) & 63;
        int j = fidx & 7;
        int k = (chunk >> 3) * 32 + ((lane >> 4) & 3) * 8 + j;
        int n = (chunk & 7) * 16 + (lane & 15);
        const float* W = (mat < 2) ? (Wr0 + mat * 16384) : (Wr1 + (mat - 2) * 16384);
        Wtf[idx] = f2bf(W[k * 128 + n]);
    }
}

// ---- fused 2-layer, TRANSPOSED formulation: D = W^T (A-op) x feat^T (B-op).
// Each lane owns ONE output row (lane&15 within its wave's 16-row strip) and
// 4 consecutive output cols per accumulator quad -> float4 stores, b64 h1
// hand-off, single scale lookup. All LDS A-frag reads are base+lane*16B
// (conflict-free). h1 (B-frag order) overlays the dead W0 region: 64 KB LDS.
__global__ __launch_bounds__(512, 4) void fused2(
    const float* __restrict__ featA, const float* __restrict__ featB,
    const u16* __restrict__ Wtf, const u32* __restrict__ bm,
    const float* __restrict__ br0, const float* __restrict__ br1,
    float* __restrict__ out) {
    __shared__ u16 lds[32768];            // [W0f: 16384][W1f: 16384]; h1 overlays W0f

    const int type = (blockIdx.x >= 782) ? 1 : 0;
    const int blk = blockIdx.x - type * 782;
    const float* feat = type ? featB : featA;
    const u16* W0g = Wtf + type * 16384;
    const u16* W1g = Wtf + (2 + type) * 16384;
    const float* b0 = br0 + type * 128;
    const float* b1 = br1 + type * 128;
    float* outp = out + (size_t)type * NN * 128;

    const int t = threadIdx.x;
    const int wave = t >> 6, lane = t & 63;
    const int quad = lane >> 4, mrow = lane & 15;
    const int row = blk * 128 + wave * 16 + mrow;   // this lane's output row
    const int rc = (row < NN) ? row : (NN - 1);

    // stage both W frag buffers: linear, coalesced, conflict-free
#pragma unroll
    for (int i = 0; i < 4; ++i) {
        int off = (i * 512 + t) * 8;
        *(shortx8*)&lds[off] = *(const shortx8*)&W0g[off];
        *(shortx8*)&lds[16384 + off] = *(const shortx8*)&W1g[off];
    }

    // feat B-fragments: B[k][m]: k = ks*32 + quad*8 + j, m = row
    shortx8 bfrag[4];
    {
        const float* arow = feat + (size_t)rc * 128;
#pragma unroll
        for (int ks = 0; ks < 4; ++ks) {
            floatx4 f0 = *(const floatx4*)(arow + ks * 32 + quad * 8);
            floatx4 f1 = *(const floatx4*)(arow + ks * 32 + quad * 8 + 4);
            union { shortx8 v; u16 u[8]; } uu;
            uu.u[0] = f2bf(f0[0]); uu.u[1] = f2bf(f0[1]);
            uu.u[2] = f2bf(f0[2]); uu.u[3] = f2bf(f0[3]);
            uu.u[4] = f2bf(f1[0]); uu.u[5] = f2bf(f1[1]);
            uu.u[6] = f2bf(f1[2]); uu.u[7] = f2bf(f1[3]);
            bfrag[ks] = uu.v;
        }
    }

    // per-row scale from degree bitmask (same both layers; one lookup/lane)
    float scl;
    {
        int w = rc >> 5, s = rc & 31;
        if (type) {
            float ab = (float)((bm[3200 + w] >> s) & 1u);
            scl = (1.0f + ab) * 0.5f;
        } else {
            float aa = (float)((bm[w] >> s) & 1u);
            float ba = (float)((bm[6400 + w] >> s) & 1u);
            scl = (1.0f + aa + ba) * (1.0f / 3.0f);
        }
    }

    __syncthreads();   // W staged

    // ---- GEMM1: acc[nt] = W0^T tile(nt) x feat^T   (A-frags contiguous from LDS)
    floatx4 acc[8];
#pragma unroll
    for (int nt = 0; nt < 8; ++nt) acc[nt] = (floatx4){0.f, 0.f, 0.f, 0.f};
#pragma unroll
    for (int ks = 0; ks < 4; ++ks)
#pragma unroll
        for (int nt = 0; nt < 8; ++nt) {
            shortx8 af = *(const shortx8*)&lds[((ks * 8 + nt) << 9) + lane * 8];
            acc[nt] = __builtin_amdgcn_mfma_f32_16x16x32_bf16(af, bfrag[ks], acc[nt], 0, 0, 0);
        }

    __syncthreads();   // all W0 reads done; h1 overlays W0f

    // epilogue1: h1[row][n1] = relu((acc + b0[n1]) * scl), written directly in
    // GEMM2 B-frag order into this wave's private 2048-u16 region.
    const int h1base = wave * 2048;
#pragma unroll
    for (int nt = 0; nt < 8; ++nt) {
        floatx4 bv = *(const floatx4*)(b0 + nt * 16 + quad * 4);
        ushortx4 p;
#pragma unroll
        for (int r = 0; r < 4; ++r)
            p[r] = f2bf(fmaxf((acc[nt][r] + bv[r]) * scl, 0.0f));
        int q2 = (2 * nt + (quad >> 1)) & 3;
        int addr = h1base + (nt >> 1) * 512 + q2 * 128 + mrow * 8 + (quad & 1) * 4;
        *(ushortx4*)&lds[addr] = p;
    }

    // h1 B-fragments (wave-private region: no block barrier needed)
    shortx8 h1b[4];
#pragma unroll
    for (int ks = 0; ks < 4; ++ks)
        h1b[ks] = *(const shortx8*)&lds[h1base + ks * 512 + lane * 8];

    // ---- GEMM2: acc2[nt] = W1^T tile(nt) x h1^T
    floatx4 acc2[8];
#pragma unroll
    for (int nt = 0; nt < 8; ++nt) acc2[nt] = (floatx4){0.f, 0.f, 0.f, 0.f};
#pragma unroll
    for (int ks = 0; ks < 4; ++ks)
#pragma unroll
        for (int nt = 0; nt < 8; ++nt) {
            shortx8 af = *(const shortx8*)&lds[16384 + ((ks * 8 + nt) << 9) + lane * 8];
            acc2[nt] = __builtin_amdgcn_mfma_f32_16x16x32_bf16(af, h1b[ks], acc2[nt], 0, 0, 0);
        }

    // epilogue2: lane stores its row, 8 x float4 (consecutive cols per quad)
    if (row < NN) {
        float* orow = outp + (size_t)row * 128;
#pragma unroll
        for (int nt = 0; nt < 8; ++nt) {
            floatx4 bv = *(const floatx4*)(b1 + nt * 16 + quad * 4);
            floatx4 o;
#pragma unroll
            for (int r = 0; r < 4; ++r)
                o[r] = fmaxf((acc2[nt][r] + bv[r]) * scl, 0.0f);
            *(floatx4*)(orow + nt * 16 + quad * 4) = o;
        }
    }
}

extern "C" void kernel_launch(void* const* d_in, const int* in_sizes, int n_in,
                              void* d_out, int out_size, void* d_ws, size_t ws_size,
                              hipStream_t stream) {
    (void)in_sizes; (void)n_in; (void)out_size; (void)ws_size;
    const float* featA = (const float*)d_in[0];
    const float* featB = (const float*)d_in[1];
    const int* dst_aa = (const int*)d_in[3];
    const int* dst_ab = (const int*)d_in[5];
    const int* dst_ba = (const int*)d_in[7];
    const float* Wr0 = (const float*)d_in[10];
    const float* br0 = (const float*)d_in[11];
    const float* Wr1 = (const float*)d_in[16];
    const float* br1 = (const float*)d_in[17];

    char* ws = (char*)d_ws;
    u16* Wtf = (u16*)ws;                         // 4*16384*2 = 128 KB
    u32* bm = (u32*)(ws + 131072);               // 3*3200 u32 = 38400 B

    hipMemsetAsync(bm, 0, 3 * 3200 * sizeof(u32), stream);
    prep<<<EBLK + 256, 256, 0, stream>>>(dst_aa, dst_ab, dst_ba, bm, Wr0, Wr1, Wtf);
    fused2<<<2 * 782, 512, 0, stream>>>(featA, featB, Wtf, bm, br0, br1, (float*)d_out);
}